// Round 15
// baseline (148.087 us; speedup 1.0000x reference)
//
#include <hip/hip_runtime.h>
#include <math.h>

// 2-layer GCN: block-local LDS counting-sort multisplit (128-node buckets) ->
// per-bucket LDS counting sort + degree-sorted node permutation -> CSR gather
// aggregation (8 lanes/node, degree-balanced waves, unroll-2, shfl combine).
// bf16 message rows (32B). N=100000, E=3200000.
// Entry packed: (dst&127)<<17 | src (src < 2^17).

#define F_IN 132
#define F1   16
#define F2   10
#define BSH  7
#define BSPAN 128
#define NB   782           // ceil(100000/128)
#define CAP  4608          // mean 4096 entries/bucket + 8 sigma
#define SPB  12500         // edges per split block = E/256
#define SPLIT_BLOCKS 256

__device__ __forceinline__ unsigned short f2bf(float f) {
    unsigned u = __float_as_uint(f);
    u += 0x7FFFu + ((u >> 16) & 1u);          // round to nearest even
    return (unsigned short)(u >> 16);
}
__device__ __forceinline__ float bflo(unsigned u) { return __uint_as_float(u << 16); }
__device__ __forceinline__ float bfhi(unsigned u) { return __uint_as_float(u & 0xFFFF0000u); }

// ---- pass A: per-block LDS counting sort into per-bucket contiguous runs (R9-best form) ----
__global__ __launch_bounds__(1024) void k_split(const int* __restrict__ src,
                                                const int* __restrict__ dst,
                                                int* __restrict__ gcur,
                                                unsigned* __restrict__ entries, int E) {
    __shared__ unsigned le[SPB];    // 50 KB
    __shared__ int h0[1024];
    __shared__ int h1[1024];
    __shared__ int off[NB];
    const int t = threadIdx.x;
    const int lo = blockIdx.x * SPB;
    const int hi = min(E, lo + SPB);
    const int n4 = (hi - lo) >> 2;
    h0[t] = 0;
    __syncthreads();
    const int4* d4 = (const int4*)(dst + lo);
    const int4* s4 = (const int4*)(src + lo);
    for (int i = t; i < n4; i += 1024) {
        int4 d = d4[i];
        atomicAdd(&h0[d.x >> BSH], 1);
        atomicAdd(&h0[d.y >> BSH], 1);
        atomicAdd(&h0[d.z >> BSH], 1);
        atomicAdd(&h0[d.w >> BSH], 1);
    }
    __syncthreads();
    int c = h0[t];
    h1[t] = c;
    __syncthreads();
    for (int o = 1; o < 1024; o <<= 1) {
        int v = (t >= o) ? h1[t - o] : 0;
        __syncthreads();
        h1[t] += v;
        __syncthreads();
    }
    int excl = h1[t] - c;
    if (t < NB) {
        int g = t * CAP + (c ? atomicAdd(&gcur[t], c) : 0);
        off[t] = g - excl;
    }
    h0[t] = excl;
    __syncthreads();
    for (int i = t; i < n4; i += 1024) {
        int4 d = d4[i];
        int4 s = s4[i];
        int p;
        p = atomicAdd(&h0[d.x >> BSH], 1); le[p] = ((unsigned)(d.x & 127) << 17) | (unsigned)s.x;
        p = atomicAdd(&h0[d.y >> BSH], 1); le[p] = ((unsigned)(d.y & 127) << 17) | (unsigned)s.y;
        p = atomicAdd(&h0[d.z >> BSH], 1); le[p] = ((unsigned)(d.z & 127) << 17) | (unsigned)s.z;
        p = atomicAdd(&h0[d.w >> BSH], 1); le[p] = ((unsigned)(d.w & 127) << 17) | (unsigned)s.w;
    }
    __syncthreads();
    for (int bk = t; bk < NB; bk += 1024) {
        int s0 = bk ? h1[bk - 1] : 0;
        int e0 = h1[bk];
        unsigned* gp = entries + off[bk] + s0;
        for (int i = s0; i < e0; ++i) *gp++ = le[i];
    }
}

// ---- pass B: per-bucket counting sort (in place) -> CSR + dinv + degree-sorted perm ----
__global__ void k_sortB(const int* __restrict__ gcur, unsigned* __restrict__ entries,
                        int* __restrict__ rps, int* __restrict__ rpe,
                        float* __restrict__ dinv, int* __restrict__ perm, int N) {
    __shared__ unsigned le[CAP];
    __shared__ int hist4[4][BSPAN];
    __shared__ int cur[BSPAN];
    __shared__ int dbin[BSPAN];
    __shared__ int dcur[BSPAN];
    __shared__ int ws2[2], ws3[2];
    const int b = blockIdx.x;
    const int t = threadIdx.x;
    const int lane = t & 63, wv = t >> 6;
    const int cbase = b * CAP;
    const int cnt = gcur[b];
    for (int i = t; i < 4 * BSPAN; i += 256) ((int*)hist4)[i] = 0;
    if (t < BSPAN) dbin[t] = 0;
    __syncthreads();
    for (int i = t; i < cnt; i += 256) {
        unsigned p = entries[cbase + i];
        le[i] = p;
        atomicAdd(&hist4[wv][p >> 17], 1);
    }
    __syncthreads();
    int h = 0, v = 0;
    if (t < BSPAN) {
        h = hist4[0][t] + hist4[1][t] + hist4[2][t] + hist4[3][t];
        v = h;
        #pragma unroll
        for (int o = 1; o < 64; o <<= 1) {
            int u = __shfl_up(v, o, 64);
            if (lane >= o) v += u;
        }
        if (lane == 63) ws2[wv] = v;
        if (b * BSPAN + t < N) atomicAdd(&dbin[min(h, BSPAN - 1)], 1);
    }
    __syncthreads();
    int dc = 0, dvv = 0;
    if (t < BSPAN) {
        if (wv == 1) v += ws2[0];
        const int node = b * BSPAN + t;
        const int begl = v - h;
        cur[t] = cbase + begl;
        if (node < N) {
            rps[node] = cbase + begl;
            rpe[node] = cbase + begl + h;
            dinv[node] = rsqrtf((float)h + 1.0f);
        }
        dc = dbin[t];
        dvv = dc;
        #pragma unroll
        for (int o = 1; o < 64; o <<= 1) {
            int u = __shfl_up(dvv, o, 64);
            if (lane >= o) dvv += u;
        }
        if (lane == 63) ws3[wv] = dvv;
    }
    __syncthreads();
    if (t < BSPAN) {
        if (wv == 1) dvv += ws3[0];
        dcur[t] = dvv - dc;     // exclusive prefix of degree bins
    }
    __syncthreads();
    if (t < BSPAN) {
        const int node = b * BSPAN + t;
        if (node < N) {
            int r = atomicAdd(&dcur[min(h, BSPAN - 1)], 1);
            perm[b * BSPAN + r] = node;   // bucket-local degree-sorted order
        }
    }
    __syncthreads();
    for (int i = t; i < cnt; i += 256) {
        unsigned p = le[i];
        int pos = atomicAdd(&cur[p >> 17], 1);
        entries[pos] = p & 0x1FFFFu;
    }
}

// ---- g1 = bf16((x @ W1) * dinv[row]), row stride 16 bf16 = 32B ----
__global__ void k_xw1(const float* __restrict__ x, const float* __restrict__ W1,
                      const float* __restrict__ dinv, unsigned short* __restrict__ g1u, int N) {
    __shared__ float xs[16 * F_IN];
    __shared__ float wsm[F_IN * F1];
    const int t = threadIdx.x;
    const int base = blockIdx.x * 16;
    for (int idx = t; idx < 528; idx += 256)
        ((float4*)wsm)[idx] = ((const float4*)W1)[idx];
    int nrows = N - base; if (nrows > 16) nrows = 16;
    const float4* xp4 = (const float4*)(x + (size_t)base * F_IN);
    const int span4 = nrows * 33;
    for (int idx = t; idx < span4; idx += 256) ((float4*)xs)[idx] = xp4[idx];
    __syncthreads();
    const int r = t >> 4;
    const int c = t & 15;
    if (r < nrows) {
        float acc = 0.f;
        #pragma unroll 4
        for (int k = 0; k < F_IN; ++k) acc += xs[r * F_IN + k] * wsm[k * F1 + c];
        g1u[(size_t)(base + r) * 16 + c] = f2bf(acc * dinv[base + r]);
    }
}

#define ACCU8(qv, B) \
    acc[(B)+0] += bflo((qv).x); acc[(B)+1] += bfhi((qv).x); \
    acc[(B)+2] += bflo((qv).y); acc[(B)+3] += bfhi((qv).y); \
    acc[(B)+4] += bflo((qv).z); acc[(B)+5] += bfhi((qv).z); \
    acc[(B)+6] += bflo((qv).w); acc[(B)+7] += bfhi((qv).w);

// ---- layer-1 CSR aggregation: 8 lanes/node via degree-sorted perm, fused MLP ----
__global__ void k_agg1(const int* __restrict__ rps, const int* __restrict__ rpe,
                       const unsigned* __restrict__ ssrc, const unsigned short* __restrict__ g1u,
                       const float* __restrict__ dinv, const float* __restrict__ b1,
                       const float* __restrict__ W2, unsigned short* __restrict__ g2u,
                       const int* __restrict__ perm, int N) {
    __shared__ float w2s[F1 * F2];
    __shared__ float b1s[F1];
    if (threadIdx.x < F1 * F2) w2s[threadIdx.x] = W2[threadIdx.x];
    if (threadIdx.x < F1) b1s[threadIdx.x] = b1[threadIdx.x];
    __syncthreads();
    const int gid = blockIdx.x * blockDim.x + threadIdx.x;
    const int nid = gid >> 3;
    const int q = gid & 7;
    if (nid >= N) return;
    const int d = perm[nid];
    const int beg = rps[d], end = rpe[d];
    float acc[F1];
    #pragma unroll
    for (int j = 0; j < F1; ++j) acc[j] = 0.f;
    int e = beg + q;
    for (; e + 8 < end; e += 16) {
        int s0 = (int)ssrc[e];
        int s1 = (int)ssrc[e + 8];
        const uint4* r0 = (const uint4*)(g1u + (size_t)s0 * 16);
        const uint4* r1 = (const uint4*)(g1u + (size_t)s1 * 16);
        uint4 a0 = r0[0], a1 = r0[1];
        uint4 c0 = r1[0], c1 = r1[1];
        ACCU8(a0, 0) ACCU8(a1, 8)
        ACCU8(c0, 0) ACCU8(c1, 8)
    }
    if (e < end) {
        int s = (int)ssrc[e];
        const uint4* r = (const uint4*)(g1u + (size_t)s * 16);
        uint4 a0 = r[0], a1 = r[1];
        ACCU8(a0, 0) ACCU8(a1, 8)
    }
    if (q == 0) {   // self loop
        const uint4* r = (const uint4*)(g1u + (size_t)d * 16);
        uint4 a0 = r[0], a1 = r[1];
        ACCU8(a0, 0) ACCU8(a1, 8)
    }
    #pragma unroll
    for (int j = 0; j < F1; ++j) acc[j] += __shfl_xor(acc[j], 1);
    #pragma unroll
    for (int j = 0; j < F1; ++j) acc[j] += __shfl_xor(acc[j], 2);
    #pragma unroll
    for (int j = 0; j < F1; ++j) acc[j] += __shfl_xor(acc[j], 4);
    if (q == 0) {
        const float dv = dinv[d];
        float tt[F1];
        #pragma unroll
        for (int j = 0; j < F1; ++j) {
            float v = dv * acc[j] + b1s[j];
            tt[j] = v > 0.f ? v : 0.f;
        }
        float o[F2];
        #pragma unroll
        for (int c = 0; c < F2; ++c) {
            float a = 0.f;
            #pragma unroll
            for (int j = 0; j < F1; ++j) a += tt[j] * w2s[j * F2 + c];
            o[c] = dv * a;
        }
        unsigned w0 = ((unsigned)f2bf(o[1]) << 16) | f2bf(o[0]);
        unsigned w1 = ((unsigned)f2bf(o[3]) << 16) | f2bf(o[2]);
        unsigned w2 = ((unsigned)f2bf(o[5]) << 16) | f2bf(o[4]);
        unsigned w3 = ((unsigned)f2bf(o[7]) << 16) | f2bf(o[6]);
        unsigned w4 = ((unsigned)f2bf(o[9]) << 16) | f2bf(o[8]);
        uint4* op = (uint4*)(g2u + (size_t)d * 16);
        op[0] = make_uint4(w0, w1, w2, w3);
        op[1] = make_uint4(w4, 0u, 0u, 0u);
    }
}

// ---- layer-2 CSR aggregation: 8 lanes/node via perm, fused log_softmax ----
__global__ void k_agg2(const int* __restrict__ rps, const int* __restrict__ rpe,
                       const unsigned* __restrict__ ssrc, const unsigned short* __restrict__ g2u,
                       const float* __restrict__ dinv, const float* __restrict__ b2,
                       float* __restrict__ out, const int* __restrict__ perm, int N) {
    __shared__ float b2s[F2];
    if (threadIdx.x < F2) b2s[threadIdx.x] = b2[threadIdx.x];
    __syncthreads();
    const int gid = blockIdx.x * blockDim.x + threadIdx.x;
    const int nid = gid >> 3;
    const int q = gid & 7;
    if (nid >= N) return;
    const int d = perm[nid];
    const int beg = rps[d], end = rpe[d];
    float acc[F2];
    #pragma unroll
    for (int c = 0; c < F2; ++c) acc[c] = 0.f;
    int e = beg + q;
    for (; e + 8 < end; e += 16) {
        int s0 = (int)ssrc[e];
        int s1 = (int)ssrc[e + 8];
        const unsigned short* p0 = g2u + (size_t)s0 * 16;
        const unsigned short* p1 = g2u + (size_t)s1 * 16;
        uint4 a0 = *(const uint4*)(p0);
        unsigned a4 = *(const unsigned*)(p0 + 8);
        uint4 c0 = *(const uint4*)(p1);
        unsigned c4 = *(const unsigned*)(p1 + 8);
        ACCU8(a0, 0)
        acc[8] += bflo(a4); acc[9] += bfhi(a4);
        ACCU8(c0, 0)
        acc[8] += bflo(c4); acc[9] += bfhi(c4);
    }
    if (e < end) {
        int s = (int)ssrc[e];
        const unsigned short* p = g2u + (size_t)s * 16;
        uint4 a0 = *(const uint4*)(p);
        unsigned a4 = *(const unsigned*)(p + 8);
        ACCU8(a0, 0)
        acc[8] += bflo(a4); acc[9] += bfhi(a4);
    }
    if (q == 0) {   // self loop
        const unsigned short* p = g2u + (size_t)d * 16;
        uint4 a0 = *(const uint4*)(p);
        unsigned a4 = *(const unsigned*)(p + 8);
        ACCU8(a0, 0)
        acc[8] += bflo(a4); acc[9] += bfhi(a4);
    }
    #pragma unroll
    for (int c = 0; c < F2; ++c) acc[c] += __shfl_xor(acc[c], 1);
    #pragma unroll
    for (int c = 0; c < F2; ++c) acc[c] += __shfl_xor(acc[c], 2);
    #pragma unroll
    for (int c = 0; c < F2; ++c) acc[c] += __shfl_xor(acc[c], 4);
    if (q == 0) {
        const float dv = dinv[d];
        float v[F2];
        float m = -INFINITY;
        #pragma unroll
        for (int c = 0; c < F2; ++c) {
            v[c] = dv * acc[c] + b2s[c];
            m = fmaxf(m, v[c]);
        }
        float ssum = 0.f;
        #pragma unroll
        for (int c = 0; c < F2; ++c) ssum += expf(v[c] - m);
        float ls = logf(ssum);
        float* op = out + (size_t)d * F2;
        *(float4*)(op)     = make_float4(v[0]-m-ls, v[1]-m-ls, v[2]-m-ls, v[3]-m-ls);
        *(float4*)(op + 4) = make_float4(v[4]-m-ls, v[5]-m-ls, v[6]-m-ls, v[7]-m-ls);
        *(float2*)(op + 8) = make_float2(v[8]-m-ls, v[9]-m-ls);
    }
}

extern "C" void kernel_launch(void* const* d_in, const int* in_sizes, int n_in,
                              void* d_out, int out_size, void* d_ws, size_t ws_size,
                              hipStream_t stream) {
    const float* x  = (const float*)d_in[0];
    const int*   ei = (const int*)  d_in[1];
    const float* W1 = (const float*)d_in[2];
    const float* b1 = (const float*)d_in[3];
    const float* W2 = (const float*)d_in[4];
    const float* b2 = (const float*)d_in[5];
    float* out = (float*)d_out;

    const int N = in_sizes[0] / F_IN;       // 100000
    const int E = in_sizes[1] / 2;          // 3200000
    const int* src = ei;
    const int* dst = ei + E;

    // ---- workspace (~23 MB) ----
    char* w = (char*)d_ws;
    int*            gcur    = (int*)w;            w += ((size_t)NB * 4 + 255) & ~255ull;
    int*            rps     = (int*)w;            w += ((size_t)N * 4 + 255) & ~255ull;
    int*            rpe     = (int*)w;            w += ((size_t)N * 4 + 255) & ~255ull;
    float*          dinv    = (float*)w;          w += ((size_t)N * 4 + 255) & ~255ull;
    int*            perm    = (int*)w;            w += ((size_t)N * 4 + 255) & ~255ull;
    unsigned short* g1u     = (unsigned short*)w; w += ((size_t)N * 16 * 2 + 255) & ~255ull;
    unsigned short* g2u     = (unsigned short*)w; w += ((size_t)N * 16 * 2 + 255) & ~255ull;
    unsigned*       entries = (unsigned*)w;       // NB*CAP*4 = 14.4 MB

    (void)hipMemsetAsync(gcur, 0, (size_t)NB * 4, stream);
    k_split<<<SPLIT_BLOCKS, 1024, 0, stream>>>(src, dst, gcur, entries, E);
    k_sortB<<<NB, 256, 0, stream>>>(gcur, entries, rps, rpe, dinv, perm, N);
    k_xw1  <<<(N + 15) / 16, 256, 0, stream>>>(x, W1, dinv, g1u, N);
    k_agg1 <<<(8 * N + 255) / 256, 256, 0, stream>>>(rps, rpe, entries, g1u, dinv, b1, W2, g2u, perm, N);
    k_agg2 <<<(8 * N + 255) / 256, 256, 0, stream>>>(rps, rpe, entries, g2u, dinv, b2, out, perm, N);
}

// Round 16
// 138.473 us; speedup vs baseline: 1.0694x; 1.0694x over previous
//
#include <hip/hip_runtime.h>
#include <math.h>

// 2-layer GCN: block-local LDS counting-sort multisplit (128-node buckets) ->
// per-bucket LDS counting sort (shfl-scan) -> CSR gather aggregation,
// 8 lanes/node, unroll-2, shfl-butterfly combine. bf16 message rows (32B).
// Packed rowptr int2{beg,end}. N=100000, E=3200000.
// Entry packed: (dst&127)<<17 | src (src < 2^17).

#define F_IN 132
#define F1   16
#define F2   10
#define BSH  7
#define BSPAN 128
#define NB   782           // ceil(100000/128)
#define CAP  4608          // mean 4096 entries/bucket + 8 sigma
#define SPB  12500         // edges per split block = E/256
#define SPLIT_BLOCKS 256

__device__ __forceinline__ unsigned short f2bf(float f) {
    unsigned u = __float_as_uint(f);
    u += 0x7FFFu + ((u >> 16) & 1u);          // round to nearest even
    return (unsigned short)(u >> 16);
}
__device__ __forceinline__ float bflo(unsigned u) { return __uint_as_float(u << 16); }
__device__ __forceinline__ float bfhi(unsigned u) { return __uint_as_float(u & 0xFFFF0000u); }

// ---- pass A: per-block LDS counting sort into per-bucket contiguous runs (R9 form) ----
__global__ __launch_bounds__(1024) void k_split(const int* __restrict__ src,
                                                const int* __restrict__ dst,
                                                int* __restrict__ gcur,
                                                unsigned* __restrict__ entries, int E) {
    __shared__ unsigned le[SPB];    // 50 KB
    __shared__ int h0[1024];
    __shared__ int h1[1024];
    __shared__ int off[NB];
    const int t = threadIdx.x;
    const int lo = blockIdx.x * SPB;
    const int hi = min(E, lo + SPB);
    const int n4 = (hi - lo) >> 2;
    h0[t] = 0;
    __syncthreads();
    const int4* d4 = (const int4*)(dst + lo);
    const int4* s4 = (const int4*)(src + lo);
    for (int i = t; i < n4; i += 1024) {
        int4 d = d4[i];
        atomicAdd(&h0[d.x >> BSH], 1);
        atomicAdd(&h0[d.y >> BSH], 1);
        atomicAdd(&h0[d.z >> BSH], 1);
        atomicAdd(&h0[d.w >> BSH], 1);
    }
    __syncthreads();
    int c = h0[t];
    h1[t] = c;
    __syncthreads();
    for (int o = 1; o < 1024; o <<= 1) {
        int v = (t >= o) ? h1[t - o] : 0;
        __syncthreads();
        h1[t] += v;
        __syncthreads();
    }
    int excl = h1[t] - c;
    if (t < NB) {
        int g = t * CAP + (c ? atomicAdd(&gcur[t], c) : 0);
        off[t] = g - excl;
    }
    h0[t] = excl;
    __syncthreads();
    for (int i = t; i < n4; i += 1024) {
        int4 d = d4[i];
        int4 s = s4[i];
        int p;
        p = atomicAdd(&h0[d.x >> BSH], 1); le[p] = ((unsigned)(d.x & 127) << 17) | (unsigned)s.x;
        p = atomicAdd(&h0[d.y >> BSH], 1); le[p] = ((unsigned)(d.y & 127) << 17) | (unsigned)s.y;
        p = atomicAdd(&h0[d.z >> BSH], 1); le[p] = ((unsigned)(d.z & 127) << 17) | (unsigned)s.z;
        p = atomicAdd(&h0[d.w >> BSH], 1); le[p] = ((unsigned)(d.w & 127) << 17) | (unsigned)s.w;
    }
    __syncthreads();
    for (int bk = t; bk < NB; bk += 1024) {
        int s0 = bk ? h1[bk - 1] : 0;
        int e0 = h1[bk];
        unsigned* gp = entries + off[bk] + s0;
        for (int i = s0; i < e0; ++i) *gp++ = le[i];
    }
}

// ---- pass B: per-bucket counting sort (in place) -> packed CSR int2 + dinv ----
__global__ void k_sortB(const int* __restrict__ gcur, unsigned* __restrict__ entries,
                        int2* __restrict__ rp2, float* __restrict__ dinv, int N) {
    __shared__ unsigned le[CAP];
    __shared__ int hist4[4][BSPAN];
    __shared__ int cur[BSPAN];
    __shared__ int ws2[2];
    const int b = blockIdx.x;
    const int t = threadIdx.x;
    const int lane = t & 63, wv = t >> 6;
    const int cbase = b * CAP;
    const int cnt = gcur[b];
    for (int i = t; i < 4 * BSPAN; i += 256) ((int*)hist4)[i] = 0;
    __syncthreads();
    for (int i = t; i < cnt; i += 256) {
        unsigned p = entries[cbase + i];
        le[i] = p;
        atomicAdd(&hist4[wv][p >> 17], 1);
    }
    __syncthreads();
    int h = 0, v = 0;
    if (t < BSPAN) {
        h = hist4[0][t] + hist4[1][t] + hist4[2][t] + hist4[3][t];
        v = h;
        #pragma unroll
        for (int o = 1; o < 64; o <<= 1) {
            int u = __shfl_up(v, o, 64);
            if (lane >= o) v += u;
        }
        if (lane == 63) ws2[wv] = v;
    }
    __syncthreads();
    if (t < BSPAN) {
        if (wv == 1) v += ws2[0];
        const int node = b * BSPAN + t;
        const int begl = v - h;
        cur[t] = cbase + begl;
        if (node < N) {
            rp2[node] = make_int2(cbase + begl, cbase + begl + h);
            dinv[node] = rsqrtf((float)h + 1.0f);
        }
    }
    __syncthreads();
    for (int i = t; i < cnt; i += 256) {
        unsigned p = le[i];
        int pos = atomicAdd(&cur[p >> 17], 1);
        entries[pos] = p & 0x1FFFFu;
    }
}

// ---- g1 = bf16((x @ W1) * dinv[row]), row stride 16 bf16 = 32B ----
__global__ void k_xw1(const float* __restrict__ x, const float* __restrict__ W1,
                      const float* __restrict__ dinv, unsigned short* __restrict__ g1u, int N) {
    __shared__ float xs[16 * F_IN];
    __shared__ float wsm[F_IN * F1];
    const int t = threadIdx.x;
    const int base = blockIdx.x * 16;
    for (int idx = t; idx < 528; idx += 256)
        ((float4*)wsm)[idx] = ((const float4*)W1)[idx];
    int nrows = N - base; if (nrows > 16) nrows = 16;
    const float4* xp4 = (const float4*)(x + (size_t)base * F_IN);
    const int span4 = nrows * 33;
    for (int idx = t; idx < span4; idx += 256) ((float4*)xs)[idx] = xp4[idx];
    __syncthreads();
    const int r = t >> 4;
    const int c = t & 15;
    if (r < nrows) {
        float acc = 0.f;
        #pragma unroll 4
        for (int k = 0; k < F_IN; ++k) acc += xs[r * F_IN + k] * wsm[k * F1 + c];
        g1u[(size_t)(base + r) * 16 + c] = f2bf(acc * dinv[base + r]);
    }
}

#define ACCU8(qv, B) \
    acc[(B)+0] += bflo((qv).x); acc[(B)+1] += bfhi((qv).x); \
    acc[(B)+2] += bflo((qv).y); acc[(B)+3] += bfhi((qv).y); \
    acc[(B)+4] += bflo((qv).z); acc[(B)+5] += bfhi((qv).z); \
    acc[(B)+6] += bflo((qv).w); acc[(B)+7] += bfhi((qv).w);

// ---- layer-1 CSR aggregation: 8 lanes/node, unroll-2, shfl combine, fused MLP ----
__global__ void k_agg1(const int2* __restrict__ rp2, const unsigned* __restrict__ ssrc,
                       const unsigned short* __restrict__ g1u, const float* __restrict__ dinv,
                       const float* __restrict__ b1, const float* __restrict__ W2,
                       unsigned short* __restrict__ g2u, int N) {
    __shared__ float w2s[F1 * F2];
    __shared__ float b1s[F1];
    if (threadIdx.x < F1 * F2) w2s[threadIdx.x] = W2[threadIdx.x];
    if (threadIdx.x < F1) b1s[threadIdx.x] = b1[threadIdx.x];
    __syncthreads();
    const int gid = blockIdx.x * blockDim.x + threadIdx.x;
    const int d = gid >> 3;
    const int q = gid & 7;
    if (d >= N) return;
    const int2 rp = rp2[d];
    const int beg = rp.x, end = rp.y;
    float acc[F1];
    #pragma unroll
    for (int j = 0; j < F1; ++j) acc[j] = 0.f;
    int e = beg + q;
    for (; e + 8 < end; e += 16) {
        int s0 = (int)ssrc[e];
        int s1 = (int)ssrc[e + 8];
        const uint4* r0 = (const uint4*)(g1u + (size_t)s0 * 16);
        const uint4* r1 = (const uint4*)(g1u + (size_t)s1 * 16);
        uint4 a0 = r0[0], a1 = r0[1];
        uint4 c0 = r1[0], c1 = r1[1];
        ACCU8(a0, 0) ACCU8(a1, 8)
        ACCU8(c0, 0) ACCU8(c1, 8)
    }
    if (e < end) {
        int s = (int)ssrc[e];
        const uint4* r = (const uint4*)(g1u + (size_t)s * 16);
        uint4 a0 = r[0], a1 = r[1];
        ACCU8(a0, 0) ACCU8(a1, 8)
    }
    if (q == 0) {   // self loop
        const uint4* r = (const uint4*)(g1u + (size_t)d * 16);
        uint4 a0 = r[0], a1 = r[1];
        ACCU8(a0, 0) ACCU8(a1, 8)
    }
    #pragma unroll
    for (int j = 0; j < F1; ++j) acc[j] += __shfl_xor(acc[j], 1);
    #pragma unroll
    for (int j = 0; j < F1; ++j) acc[j] += __shfl_xor(acc[j], 2);
    #pragma unroll
    for (int j = 0; j < F1; ++j) acc[j] += __shfl_xor(acc[j], 4);
    if (q == 0) {
        const float dv = dinv[d];
        float tt[F1];
        #pragma unroll
        for (int j = 0; j < F1; ++j) {
            float v = dv * acc[j] + b1s[j];
            tt[j] = v > 0.f ? v : 0.f;
        }
        float o[F2];
        #pragma unroll
        for (int c = 0; c < F2; ++c) {
            float a = 0.f;
            #pragma unroll
            for (int j = 0; j < F1; ++j) a += tt[j] * w2s[j * F2 + c];
            o[c] = dv * a;
        }
        unsigned w0 = ((unsigned)f2bf(o[1]) << 16) | f2bf(o[0]);
        unsigned w1 = ((unsigned)f2bf(o[3]) << 16) | f2bf(o[2]);
        unsigned w2 = ((unsigned)f2bf(o[5]) << 16) | f2bf(o[4]);
        unsigned w3 = ((unsigned)f2bf(o[7]) << 16) | f2bf(o[6]);
        unsigned w4 = ((unsigned)f2bf(o[9]) << 16) | f2bf(o[8]);
        uint4* op = (uint4*)(g2u + (size_t)d * 16);
        op[0] = make_uint4(w0, w1, w2, w3);
        op[1] = make_uint4(w4, 0u, 0u, 0u);
    }
}

// ---- layer-2 CSR aggregation: 8 lanes/node, unroll-2, shfl combine, log_softmax ----
__global__ void k_agg2(const int2* __restrict__ rp2, const unsigned* __restrict__ ssrc,
                       const unsigned short* __restrict__ g2u, const float* __restrict__ dinv,
                       const float* __restrict__ b2, float* __restrict__ out, int N) {
    __shared__ float b2s[F2];
    if (threadIdx.x < F2) b2s[threadIdx.x] = b2[threadIdx.x];
    __syncthreads();
    const int gid = blockIdx.x * blockDim.x + threadIdx.x;
    const int d = gid >> 3;
    const int q = gid & 7;
    if (d >= N) return;
    const int2 rp = rp2[d];
    const int beg = rp.x, end = rp.y;
    float acc[F2];
    #pragma unroll
    for (int c = 0; c < F2; ++c) acc[c] = 0.f;
    int e = beg + q;
    for (; e + 8 < end; e += 16) {
        int s0 = (int)ssrc[e];
        int s1 = (int)ssrc[e + 8];
        const unsigned short* p0 = g2u + (size_t)s0 * 16;
        const unsigned short* p1 = g2u + (size_t)s1 * 16;
        uint4 a0 = *(const uint4*)(p0);
        unsigned a4 = *(const unsigned*)(p0 + 8);
        uint4 c0 = *(const uint4*)(p1);
        unsigned c4 = *(const unsigned*)(p1 + 8);
        ACCU8(a0, 0)
        acc[8] += bflo(a4); acc[9] += bfhi(a4);
        ACCU8(c0, 0)
        acc[8] += bflo(c4); acc[9] += bfhi(c4);
    }
    if (e < end) {
        int s = (int)ssrc[e];
        const unsigned short* p = g2u + (size_t)s * 16;
        uint4 a0 = *(const uint4*)(p);
        unsigned a4 = *(const unsigned*)(p + 8);
        ACCU8(a0, 0)
        acc[8] += bflo(a4); acc[9] += bfhi(a4);
    }
    if (q == 0) {   // self loop
        const unsigned short* p = g2u + (size_t)d * 16;
        uint4 a0 = *(const uint4*)(p);
        unsigned a4 = *(const unsigned*)(p + 8);
        ACCU8(a0, 0)
        acc[8] += bflo(a4); acc[9] += bfhi(a4);
    }
    #pragma unroll
    for (int c = 0; c < F2; ++c) acc[c] += __shfl_xor(acc[c], 1);
    #pragma unroll
    for (int c = 0; c < F2; ++c) acc[c] += __shfl_xor(acc[c], 2);
    #pragma unroll
    for (int c = 0; c < F2; ++c) acc[c] += __shfl_xor(acc[c], 4);
    if (q == 0) {
        const float dv = dinv[d];
        float v[F2];
        float m = -INFINITY;
        #pragma unroll
        for (int c = 0; c < F2; ++c) {
            v[c] = dv * acc[c] + b2s[c];
            m = fmaxf(m, v[c]);
        }
        float ssum = 0.f;
        #pragma unroll
        for (int c = 0; c < F2; ++c) ssum += expf(v[c] - m);
        float ls = logf(ssum);
        float* op = out + (size_t)d * F2;
        *(float4*)(op)     = make_float4(v[0]-m-ls, v[1]-m-ls, v[2]-m-ls, v[3]-m-ls);
        *(float4*)(op + 4) = make_float4(v[4]-m-ls, v[5]-m-ls, v[6]-m-ls, v[7]-m-ls);
        *(float2*)(op + 8) = make_float2(v[8]-m-ls, v[9]-m-ls);
    }
}

extern "C" void kernel_launch(void* const* d_in, const int* in_sizes, int n_in,
                              void* d_out, int out_size, void* d_ws, size_t ws_size,
                              hipStream_t stream) {
    const float* x  = (const float*)d_in[0];
    const int*   ei = (const int*)  d_in[1];
    const float* W1 = (const float*)d_in[2];
    const float* b1 = (const float*)d_in[3];
    const float* W2 = (const float*)d_in[4];
    const float* b2 = (const float*)d_in[5];
    float* out = (float*)d_out;

    const int N = in_sizes[0] / F_IN;       // 100000
    const int E = in_sizes[1] / 2;          // 3200000
    const int* src = ei;
    const int* dst = ei + E;

    // ---- workspace (~22 MB) ----
    char* w = (char*)d_ws;
    int*            gcur    = (int*)w;            w += ((size_t)NB * 4 + 255) & ~255ull;
    int2*           rp2     = (int2*)w;           w += ((size_t)N * 8 + 255) & ~255ull;
    float*          dinv    = (float*)w;          w += ((size_t)N * 4 + 255) & ~255ull;
    unsigned short* g1u     = (unsigned short*)w; w += ((size_t)N * 16 * 2 + 255) & ~255ull;
    unsigned short* g2u     = (unsigned short*)w; w += ((size_t)N * 16 * 2 + 255) & ~255ull;
    unsigned*       entries = (unsigned*)w;       // NB*CAP*4 = 14.4 MB

    (void)hipMemsetAsync(gcur, 0, (size_t)NB * 4, stream);
    k_split<<<SPLIT_BLOCKS, 1024, 0, stream>>>(src, dst, gcur, entries, E);
    k_sortB<<<NB, 256, 0, stream>>>(gcur, entries, rp2, dinv, N);
    k_xw1  <<<(N + 15) / 16, 256, 0, stream>>>(x, W1, dinv, g1u, N);
    k_agg1 <<<(8 * N + 255) / 256, 256, 0, stream>>>(rp2, entries, g1u, dinv, b1, W2, g2u, N);
    k_agg2 <<<(8 * N + 255) / 256, 256, 0, stream>>>(rp2, entries, g2u, dinv, b2, out, N);
}